// Round 6
// baseline (142.552 us; speedup 1.0000x reference)
//
#include <hip/hip_runtime.h>
#include <math.h>

typedef _Float16 half8 __attribute__((ext_vector_type(8)));
typedef _Float16 half4v __attribute__((ext_vector_type(4)));
typedef float floatx4 __attribute__((ext_vector_type(4)));

// ---------------------------------------------------------------------------
// Prep: hih = (f16)(E@W1a + b1), hjh = (f16)(E@W1b); W2/W3 pre-swizzled into
// MFMA fragment order. blocks 0..1023: one (b,s) row (256 thr: t<128 -> hi
// half, t>=128 -> hj half). block 1024: W2frag. block 1025: W3frag.
// ---------------------------------------------------------------------------
__global__ __launch_bounds__(256) void prep_kernel(
    const float* __restrict__ E,
    const float* __restrict__ W1,
    const float* __restrict__ b1,
    const float* __restrict__ W2,
    const float* __restrict__ W3,
    _Float16* __restrict__ hih,
    _Float16* __restrict__ hjh,
    _Float16* __restrict__ W2frag,
    _Float16* __restrict__ W3frag)
{
    const int blk = blockIdx.x;
    const int t = threadIdx.x;
    if (blk < 1024) {
        __shared__ float sE[128];
        if (t < 128) sE[t] = E[blk*128 + t];
        __syncthreads();
        const int half = t >> 7;       // 0: hi (with b1), 1: hj
        const int k = t & 127;
        float acc = half ? 0.f : b1[k];
        const float* w1col = &W1[half*128*128 + k];
        #pragma unroll 8
        for (int d = 0; d < 128; ++d)
            acc = fmaf(sE[d], w1col[d*128], acc);
        if (half == 0) hih[blk*128 + k] = (_Float16)acc;
        else           hjh[blk*128 + k] = (_Float16)acc;
    } else if (blk == 1024) {
        // A-frag order: frag g=((wr*4+nt)*4+ks), lane l, elem q holds
        // W2t[n][k]=W2[k][n], n=64*wr+16*nt+(l&15), k=ks*32+(l>>4)*8+q
        for (int e = t; e < 16384; e += 256) {
            int q = e & 7, l = (e >> 3) & 63, g = e >> 9;
            int wr = g >> 4, nt = (g >> 2) & 3, ks = g & 3;
            int row = 64*wr + 16*nt + (l & 15);
            int k = ks*32 + (l >> 4)*8 + q;
            W2frag[e] = (_Float16)W2[k*128 + row];
        }
    } else {
        // B-frag order: frag ks, lane l, elem q holds W3[k][n2],
        // n2=l&15, k=ks*32+(l>>4)*8+q
        for (int e = t; e < 2048; e += 256) {
            int q = e & 7, l = (e >> 3) & 63, ks = e >> 9;
            int k = ks*32 + (l >> 4)*8 + q;
            W3frag[e] = (_Float16)W3[k*16 + (l & 15)];
        }
    }
}

// ---------------------------------------------------------------------------
// Main: one block = (b, i, j0..j0+127). H fragments built IN REGISTERS from
// global f16 hih/hjh (no LDS for H, single barrier). GEMM1 transposed
// (D[n][m]); H2 through LDS (layout C->A); GEMM2; f32 output.
// ---------------------------------------------------------------------------
__global__ __launch_bounds__(256, 3) void main_kernel(
    const _Float16* __restrict__ hih,
    const _Float16* __restrict__ hjh,
    const _Float16* __restrict__ W2frag,
    const _Float16* __restrict__ W3frag,
    const float* __restrict__ b2,
    const float* __restrict__ b3,
    const float* __restrict__ temps,
    const int* __restrict__ mask,
    float* __restrict__ out)
{
    constexpr int PADH = 136;            // f16 units; 272B row stride
    __shared__ _Float16 sH[128 * PADH];  // H2 only

    const int tid = threadIdx.x;
    const int bid = blockIdx.x;
    const int b  = bid >> 11;
    const int i  = (bid >> 2) & 511;
    const int j0 = (bid & 3) << 7;

    const int lane = tid & 63;
    const int wave = tid >> 6;
    const int wr = wave >> 1;   // n-strip
    const int wc = wave & 1;    // m-strip (j)
    const int lr = lane & 15;
    const int lq = lane >> 4;

    const half8 zero8 = {};
    const _Float16* hirow = &hih[(b*512 + i)*128];
    const _Float16* hjbase = &hjh[(b*512 + j0)*128];
    const half8* w2v = (const half8*)W2frag;

    // GEMM1': D[n][m] = sum_k W2[k][n] * relu(hi[k]+hj[m][k])
    floatx4 acc[4][4] = {};
    #pragma unroll
    for (int ks = 0; ks < 4; ++ks) {
        const int kb = ks*32 + lq*8;
        half8 aW[4];
        #pragma unroll
        for (int nt = 0; nt < 4; ++nt)
            aW[nt] = w2v[((wr*4 + nt)*4 + ks)*64 + lane];
        const half8 hi8 = *(const half8*)&hirow[kb];
        half8 bF[4];
        #pragma unroll
        for (int mt = 0; mt < 4; ++mt) {
            const int m = 64*wc + 16*mt + lr;
            half8 hj8 = *(const half8*)&hjbase[m*128 + kb];
            bF[mt] = __builtin_elementwise_max(hi8 + hj8, zero8);
        }
        #pragma unroll
        for (int nt = 0; nt < 4; ++nt)
            #pragma unroll
            for (int mt = 0; mt < 4; ++mt)
                acc[nt][mt] = __builtin_amdgcn_mfma_f32_16x16x32_f16(
                    aW[nt], bF[mt], acc[nt][mt], 0, 0, 0);
    }

    // H2[m][n] = relu(D + b2[n]); lane's 4 regs = 4 consecutive n -> b64 write
    #pragma unroll
    for (int nt = 0; nt < 4; ++nt) {
        const int nb = 64*wr + 16*nt + 4*lq;
        const float4 bv = *(const float4*)&b2[nb];
        #pragma unroll
        for (int mt = 0; mt < 4; ++mt) {
            const int m = 64*wc + 16*mt + lr;
            floatx4 v = acc[nt][mt];
            half4v o;
            o[0] = (_Float16)fmaxf(v[0] + bv.x, 0.f);
            o[1] = (_Float16)fmaxf(v[1] + bv.y, 0.f);
            o[2] = (_Float16)fmaxf(v[2] + bv.z, 0.f);
            o[3] = (_Float16)fmaxf(v[3] + bv.w, 0.f);
            *(half4v*)&sH[m*PADH + nb] = o;
        }
    }
    __syncthreads();   // the only barrier

    // GEMM2: D2[m][n2] = sum_n H2[m][n] * W3[n][n2]
    const half8* w3v = (const half8*)W3frag;
    floatx4 acc2[2] = {};
    const int m0 = 32*wave;
    #pragma unroll
    for (int ks = 0; ks < 4; ++ks) {
        const int k0 = ks*32 + lq*8;
        half8 bW = w3v[ks*64 + lane];
        half8 a0 = *(const half8*)&sH[(m0 + lr)*PADH + k0];
        half8 a1 = *(const half8*)&sH[(m0 + 16 + lr)*PADH + k0];
        acc2[0] = __builtin_amdgcn_mfma_f32_16x16x32_f16(a0, bW, acc2[0], 0, 0, 0);
        acc2[1] = __builtin_amdgcn_mfma_f32_16x16x32_f16(a1, bW, acc2[1], 0, 0, 0);
    }

    // Epilogue: bias = (comp + b3)*temp, mask -> -inf, float4 stores (f32 out)
    const int n2 = lr;
    const float tempv = temps[n2];
    const float b3v = b3[n2];
    const int* mrow = &mask[(b*512 + i)*512];
    float* outp = &out[(((b*16 + n2)*512) + i)*512];
    #pragma unroll
    for (int mt2 = 0; mt2 < 2; ++mt2) {
        const int j = j0 + m0 + 16*mt2 + 4*lq;
        floatx4 v = acc2[mt2];
        int4 mk = *(const int4*)&mrow[j];
        float4 res;
        res.x = mk.x ? (v[0] + b3v)*tempv : -INFINITY;
        res.y = mk.y ? (v[1] + b3v)*tempv : -INFINITY;
        res.z = mk.z ? (v[2] + b3v)*tempv : -INFINITY;
        res.w = mk.w ? (v[3] + b3v)*tempv : -INFINITY;
        *(float4*)&outp[j] = res;
    }
}

extern "C" void kernel_launch(void* const* d_in, const int* in_sizes, int n_in,
                              void* d_out, int out_size, void* d_ws, size_t ws_size,
                              hipStream_t stream)
{
    const float* E     = (const float*)d_in[0];
    const int* mask    = (const int*)d_in[1];
    const float* W1    = (const float*)d_in[2];
    const float* b1    = (const float*)d_in[3];
    const float* W2    = (const float*)d_in[4];
    const float* b2    = (const float*)d_in[5];
    const float* W3    = (const float*)d_in[6];
    const float* b3    = (const float*)d_in[7];
    const float* temps = (const float*)d_in[8];

    char* ws = (char*)d_ws;
    _Float16* hih = (_Float16*)ws;                       // 1024*128 f16 = 256KB
    _Float16* hjh = (_Float16*)(ws + 262144);            // 256KB
    _Float16* W2f = (_Float16*)(ws + 524288);            // 32KB
    _Float16* W3f = W2f + 16384;                         // 4KB

    prep_kernel<<<1026, 256, 0, stream>>>(E, W1, b1, W2, W3, hih, hjh, W2f, W3f);
    main_kernel<<<4096, 256, 0, stream>>>(hih, hjh, W2f, W3f, b2, b3, temps, mask,
                                          (float*)d_out);
}

// Round 7
// 115.427 us; speedup vs baseline: 1.2350x; 1.2350x over previous
//
#include <hip/hip_runtime.h>
#include <math.h>

typedef _Float16 half8 __attribute__((ext_vector_type(8)));
typedef _Float16 half4v __attribute__((ext_vector_type(4)));
typedef float floatx4 __attribute__((ext_vector_type(4)));

// ---------------------------------------------------------------------------
// Prep: hih = (f16)(E@W1a + b1), hjh = (f16)(E@W1b); W2/W3 pre-swizzled into
// MFMA fragment order. blocks 0..1023: one (b,s) row (256 thr: t<128 -> hi
// half, t>=128 -> hj half). block 1024: W2frag. block 1025: W3frag.
// ---------------------------------------------------------------------------
__global__ __launch_bounds__(256) void prep_kernel(
    const float* __restrict__ E,
    const float* __restrict__ W1,
    const float* __restrict__ b1,
    const float* __restrict__ W2,
    const float* __restrict__ W3,
    _Float16* __restrict__ hih,
    _Float16* __restrict__ hjh,
    _Float16* __restrict__ W2frag,
    _Float16* __restrict__ W3frag)
{
    const int blk = blockIdx.x;
    const int t = threadIdx.x;
    if (blk < 1024) {
        __shared__ float sE[128];
        if (t < 128) sE[t] = E[blk*128 + t];
        __syncthreads();
        const int half = t >> 7;       // 0: hi (with b1), 1: hj
        const int k = t & 127;
        float acc = half ? 0.f : b1[k];
        const float* w1col = &W1[half*128*128 + k];
        #pragma unroll 8
        for (int d = 0; d < 128; ++d)
            acc = fmaf(sE[d], w1col[d*128], acc);
        if (half == 0) hih[blk*128 + k] = (_Float16)acc;
        else           hjh[blk*128 + k] = (_Float16)acc;
    } else if (blk == 1024) {
        // A-frag order: frag g=((wr*4+nt)*4+ks), lane l, elem q holds
        // W2t[n][k]=W2[k][n], n=64*wr+16*nt+(l&15), k=ks*32+(l>>4)*8+q
        for (int e = t; e < 16384; e += 256) {
            int q = e & 7, l = (e >> 3) & 63, g = e >> 9;
            int wr = g >> 4, nt = (g >> 2) & 3, ks = g & 3;
            int row = 64*wr + 16*nt + (l & 15);
            int k = ks*32 + (l >> 4)*8 + q;
            W2frag[e] = (_Float16)W2[k*128 + row];
        }
    } else {
        // B-frag order: frag ks, lane l, elem q holds W3[k][n2],
        // n2=l&15, k=ks*32+(l>>4)*8+q
        for (int e = t; e < 2048; e += 256) {
            int q = e & 7, l = (e >> 3) & 63, ks = e >> 9;
            int k = ks*32 + (l >> 4)*8 + q;
            W3frag[e] = (_Float16)W3[k*16 + (l & 15)];
        }
    }
}

// ---------------------------------------------------------------------------
// Main: one block = (b, i, j0..j0+127). RAW f16 hj tile staged to padded LDS
// with pure coalesced b128 copies (no math). relu(hi+hj) fused into GEMM1
// fragment build via packed f16 ops. GEMM1 transposed (D[n][m]) -> H2 to LDS
// (C->A layout fixup), GEMM2, f32 output.
// ---------------------------------------------------------------------------
__global__ __launch_bounds__(256, 3) void main_kernel(
    const _Float16* __restrict__ hih,
    const _Float16* __restrict__ hjh,
    const _Float16* __restrict__ W2frag,
    const _Float16* __restrict__ W3frag,
    const float* __restrict__ b2,
    const float* __restrict__ b3,
    const float* __restrict__ temps,
    const int* __restrict__ mask,
    float* __restrict__ out)
{
    constexpr int PADH = 136;            // f16 units; 272B row stride
    __shared__ _Float16 sH[128 * PADH];  // raw hj tile, then reused for H2

    const int tid = threadIdx.x;
    const int bid = blockIdx.x;
    const int b  = bid >> 11;
    const int i  = (bid >> 2) & 511;
    const int j0 = (bid & 3) << 7;

    const int lane = tid & 63;
    const int wave = tid >> 6;
    const int wr = wave >> 1;   // n-strip
    const int wc = wave & 1;    // m-strip (j)
    const int lr = lane & 15;
    const int lq = lane >> 4;

    const half8 zero8 = {};
    const _Float16* hirow = &hih[(b*512 + i)*128];
    const _Float16* hjbase = &hjh[(b*512 + j0)*128];
    const half8* w2v = (const half8*)W2frag;

    // W2 A-fragments straight to registers (16 x b128, L2-hot)
    half8 aW[4][4];
    #pragma unroll
    for (int nt = 0; nt < 4; ++nt)
        #pragma unroll
        for (int ks = 0; ks < 4; ++ks)
            aW[nt][ks] = w2v[((wr*4 + nt)*4 + ks)*64 + lane];

    // hi fragments (k-dependent only): 4 x half8 per lane
    half8 hiF[4];
    #pragma unroll
    for (int ks = 0; ks < 4; ++ks)
        hiF[ks] = *(const half8*)&hirow[ks*32 + lq*8];

    // Stage raw hj tile: 4096 16B-chunks, lane-contiguous (1KB/wave/instr)
    #pragma unroll
    for (int kk = 0; kk < 8; ++kk) {
        const int c = kk*256 + tid;       // chunk id
        const int row = c >> 4, col = c & 15;
        half8 v = *(const half8*)&hjbase[row*128 + col*8];
        *(half8*)&sH[row*PADH + col*8] = v;
    }
    __syncthreads();

    // GEMM1': D[n][m] = sum_k W2[k][n] * relu(hi[k]+hj[m][k])
    floatx4 acc[4][4] = {};
    #pragma unroll
    for (int ks = 0; ks < 4; ++ks) {
        const int kb = ks*32 + lq*8;
        half8 bF[4];
        #pragma unroll
        for (int mt = 0; mt < 4; ++mt) {
            const int m = 64*wc + 16*mt + lr;
            half8 hj8 = *(const half8*)&sH[m*PADH + kb];
            bF[mt] = __builtin_elementwise_max(hiF[ks] + hj8, zero8);
        }
        #pragma unroll
        for (int nt = 0; nt < 4; ++nt)
            #pragma unroll
            for (int mt = 0; mt < 4; ++mt)
                acc[nt][mt] = __builtin_amdgcn_mfma_f32_16x16x32_f16(
                    aW[nt][ks], bF[mt], acc[nt][mt], 0, 0, 0);
    }
    __syncthreads();   // all waves done reading raw hj before overwrite

    // H2[m][n] = relu(D + b2[n]); lane's 4 regs = 4 consecutive n -> b64 write
    #pragma unroll
    for (int nt = 0; nt < 4; ++nt) {
        const int nb = 64*wr + 16*nt + 4*lq;
        const float4 bv = *(const float4*)&b2[nb];
        #pragma unroll
        for (int mt = 0; mt < 4; ++mt) {
            const int m = 64*wc + 16*mt + lr;
            floatx4 v = acc[nt][mt];
            half4v o;
            o[0] = (_Float16)fmaxf(v[0] + bv.x, 0.f);
            o[1] = (_Float16)fmaxf(v[1] + bv.y, 0.f);
            o[2] = (_Float16)fmaxf(v[2] + bv.z, 0.f);
            o[3] = (_Float16)fmaxf(v[3] + bv.w, 0.f);
            *(half4v*)&sH[m*PADH + nb] = o;
        }
    }

    // Prefetch mask while LDS settles (hides VMEM latency behind barrier)
    const int* mrow = &mask[(b*512 + i)*512];
    const int m0 = 32*wave;
    int4 mk0 = *(const int4*)&mrow[j0 + m0 + 4*lq];
    int4 mk1 = *(const int4*)&mrow[j0 + m0 + 16 + 4*lq];
    __syncthreads();

    // GEMM2: D2[m][n2] = sum_n H2[m][n] * W3[n][n2]
    const half8* w3v = (const half8*)W3frag;
    floatx4 acc2[2] = {};
    #pragma unroll
    for (int ks = 0; ks < 4; ++ks) {
        const int k0 = ks*32 + lq*8;
        half8 bW = w3v[ks*64 + lane];
        half8 a0 = *(const half8*)&sH[(m0 + lr)*PADH + k0];
        half8 a1 = *(const half8*)&sH[(m0 + 16 + lr)*PADH + k0];
        acc2[0] = __builtin_amdgcn_mfma_f32_16x16x32_f16(a0, bW, acc2[0], 0, 0, 0);
        acc2[1] = __builtin_amdgcn_mfma_f32_16x16x32_f16(a1, bW, acc2[1], 0, 0, 0);
    }

    // Epilogue: bias = (comp + b3)*temp, mask -> -inf, float4 stores (f32 out)
    const int n2 = lr;
    const float tempv = temps[n2];
    const float b3v = b3[n2];
    float* outp = &out[(((b*16 + n2)*512) + i)*512];
    {
        const int j = j0 + m0 + 4*lq;
        floatx4 v = acc2[0];
        float4 res;
        res.x = mk0.x ? (v[0] + b3v)*tempv : -INFINITY;
        res.y = mk0.y ? (v[1] + b3v)*tempv : -INFINITY;
        res.z = mk0.z ? (v[2] + b3v)*tempv : -INFINITY;
        res.w = mk0.w ? (v[3] + b3v)*tempv : -INFINITY;
        *(float4*)&outp[j] = res;
    }
    {
        const int j = j0 + m0 + 16 + 4*lq;
        floatx4 v = acc2[1];
        float4 res;
        res.x = mk1.x ? (v[0] + b3v)*tempv : -INFINITY;
        res.y = mk1.y ? (v[1] + b3v)*tempv : -INFINITY;
        res.z = mk1.z ? (v[2] + b3v)*tempv : -INFINITY;
        res.w = mk1.w ? (v[3] + b3v)*tempv : -INFINITY;
        *(float4*)&outp[j] = res;
    }
}

extern "C" void kernel_launch(void* const* d_in, const int* in_sizes, int n_in,
                              void* d_out, int out_size, void* d_ws, size_t ws_size,
                              hipStream_t stream)
{
    const float* E     = (const float*)d_in[0];
    const int* mask    = (const int*)d_in[1];
    const float* W1    = (const float*)d_in[2];
    const float* b1    = (const float*)d_in[3];
    const float* W2    = (const float*)d_in[4];
    const float* b2    = (const float*)d_in[5];
    const float* W3    = (const float*)d_in[6];
    const float* b3    = (const float*)d_in[7];
    const float* temps = (const float*)d_in[8];

    char* ws = (char*)d_ws;
    _Float16* hih = (_Float16*)ws;                       // 1024*128 f16 = 256KB
    _Float16* hjh = (_Float16*)(ws + 262144);            // 256KB
    _Float16* W2f = (_Float16*)(ws + 524288);            // 32KB
    _Float16* W3f = W2f + 16384;                         // 4KB

    prep_kernel<<<1026, 256, 0, stream>>>(E, W1, b1, W2, W3, hih, hjh, W2f, W3f);
    main_kernel<<<4096, 256, 0, stream>>>(hih, hjh, W2f, W3f, b2, b3, temps, mask,
                                          (float*)d_out);
}